// Round 6
// baseline (270.731 us; speedup 1.0000x reference)
//
#include <hip/hip_runtime.h>
#include <stdint.h>

typedef unsigned short u16;
typedef unsigned int u32;
typedef __attribute__((ext_vector_type(8))) short short8;
typedef __attribute__((ext_vector_type(4))) float floatx4;

__device__ __forceinline__ u16 f2b(float f) {
  union { float f; u32 u; } c; c.f = f;
  u32 u = c.u;
  u += 0x7fffu + ((u >> 16) & 1u);
  return (u16)(u >> 16);
}
__device__ __forceinline__ float b2f(u16 h) {
  union { u32 u; float f; } c; c.u = ((u32)h) << 16;
  return c.f;
}

// async global->LDS, 16B per lane; LDS dest is wave-uniform base + lane*16
__device__ __forceinline__ void glds16(const void* g, void* l) {
  __builtin_amdgcn_global_load_lds((__attribute__((address_space(1))) void*)g,
                                   (__attribute__((address_space(3))) void*)l, 16, 0, 0);
}

// ---------------- mega-prep: argmin parts | transposes | weight casts | zero sums ----------------
__global__ void prep_all_k(const float* __restrict__ xyz1, const float* __restrict__ xyz2,
                           float2* __restrict__ cand,
                           const float* __restrict__ f1, u16* __restrict__ f1t,
                           const float* __restrict__ f2, u16* __restrict__ f2t,
                           const float* __restrict__ w0, u16* __restrict__ w0b,
                           const float* __restrict__ w1, u16* __restrict__ w1b,
                           float* __restrict__ sums) {
  __shared__ __align__(16) char smem[9216];
  int blk = blockIdx.x, t = threadIdx.x;
  if (blk < 512) {
    float4* s2 = (float4*)smem;
    int nq = blk & 7, mq = (blk >> 3) & 7, b = blk >> 6;
    const float* x2 = xyz2 + ((size_t)b * 2048 + mq * 256) * 3;
    s2[t] = make_float4(x2[t * 3], x2[t * 3 + 1], x2[t * 3 + 2], 0.f);
    __syncthreads();
    int n0 = nq * 1024 + t;
    float px[4], py[4], pz[4];
#pragma unroll
    for (int q = 0; q < 4; q++) {
      const float* p1 = xyz1 + ((size_t)b * 8192 + n0 + q * 256) * 3;
      px[q] = p1[0]; py[q] = p1[1]; pz[q] = p1[2];
    }
    float best[4] = {3.0e38f, 3.0e38f, 3.0e38f, 3.0e38f};
    int bi[4] = {0, 0, 0, 0};
#pragma unroll 4
    for (int m = 0; m < 256; m++) {
      float4 qq = s2[m];
#pragma unroll
      for (int q = 0; q < 4; q++) {
        float dx = px[q] - qq.x, dy = py[q] - qq.y, dz = pz[q] - qq.z;
        float d = fmaf(dz, dz, fmaf(dy, dy, dx * dx));  // EXACT contraction from passing rounds
        bool c = d < best[q];
        best[q] = c ? d : best[q];
        bi[q] = c ? m : bi[q];
      }
    }
#pragma unroll
    for (int q = 0; q < 4; q++) {
      int n = n0 + q * 256;
      cand[(size_t)mq * 65536 + (size_t)b * 8192 + n] =
          make_float2(best[q], __int_as_float(mq * 256 + bi[q]));
    }
  } else if (blk < 3584) {
    const float* in; u16* out; int C, N, bx, by, bz;
    if (blk < 2560) { int rel = blk - 512;  in = f1; out = f1t; C = 128; N = 8192; bx = rel & 127; by = (rel >> 7) & 1; bz = rel >> 8; }
    else            { int rel = blk - 2560; in = f2; out = f2t; C = 256; N = 2048; bx = rel & 31;  by = (rel >> 5) & 3; bz = rel >> 7; }
    u16 (*tile)[72] = (u16(*)[72])smem;
    int c0 = by * 64, n0 = bx * 64;
    const float* src = in + ((size_t)bz * C + c0) * N + n0;
#pragma unroll
    for (int i = 0; i < 4; i++) {
      int id = t + i * 256;
      int c = id >> 4, nq = (id & 15) * 4;
      float4 v = *(const float4*)(src + (size_t)c * N + nq);
      tile[nq + 0][c] = f2b(v.x);
      tile[nq + 1][c] = f2b(v.y);
      tile[nq + 2][c] = f2b(v.z);
      tile[nq + 3][c] = f2b(v.w);
    }
    __syncthreads();
    int n = t >> 2, ch = (t & 3) * 16;
    u16* dst = out + ((size_t)bz * N + n0 + n) * C + c0 + ch;
    *(uint4*)dst = *(const uint4*)&tile[n][ch];
    *(uint4*)(dst + 8) = *(const uint4*)&tile[n][ch + 8];
  } else {
    int rel = blk - 3584;
    int i = rel * 256 + t;
    if (rel < 384) w0b[i] = f2b(w0[i]);
    else { int j = i - 98304; w1b[j] = f2b(w1[j]); }
    if (rel < 4) sums[i] = 0.f;
  }
}

// ---------------- GEMM1: A-resident LDS (128o x 384k), B streamed DIRECT to registers ----------------
// Barrier-free K-loop: each lane's MFMA B-fragment is 16 contiguous bytes of an f1t/f2t row.
// grid 256: ohalf=(bid>>3)&1, pairidx=(bid&7)|((bid>>4)<<3) -> o-pair on same XCD (r5-proven, FETCH ideal).
__global__ __launch_bounds__(512, 2) void gemm1_k(const u16* __restrict__ w0b, const u16* __restrict__ f1t,
                                                  const u16* __restrict__ f2t, const float2* __restrict__ cand,
                                                  float* __restrict__ sum0, float* __restrict__ sq0,
                                                  u16* __restrict__ y0) {
  __shared__ u16 Aw[128 * 384];     // 96KB resident weights (o-half), XOR swizzle within 8-chunk groups
  int t = threadIdx.x;
  int bid = blockIdx.x;
  int ohalf = (bid >> 3) & 1;
  int pairidx = (bid & 7) | ((bid >> 4) << 3);   // [0,128)
  int o0 = ohalf * 128;
  int lane = t & 63, wave = t >> 6;              // 8 waves
  int wrow = (wave >> 2) * 64;                   // o-offset within half (2 o-groups)
  int wp = (wave & 3) * 32;                      // p-offset (4 p-groups)
  int lr = lane & 15, lq = lane >> 4;

  // ---- A-load prologue: 12 glds16/thread, linear LDS dest; per-lane source carries the swizzle ----
#pragma unroll
  for (int it = 0; it < 12; it++) {
    u32 off = (u32)it * 8192 + (u32)t * 16;      // byte offset in Aw
    int row = off / 768;                          // 768B per row (384 u16)
    int c16 = (off - row * 768) >> 4;             // phys 16B chunk in row
    glds16(w0b + (size_t)(o0 + row) * 384 + ((c16 ^ (row & 7)) << 3),
           (char*)Aw + (size_t)it * 8192 + (size_t)wave * 1024);
  }

  float sa[4][4], qa[4][4];
#pragma unroll
  for (int i = 0; i < 4; i++)
#pragma unroll
    for (int r = 0; r < 4; r++) { sa[i][r] = 0.f; qa[i][r] = 0.f; }

  __syncthreads();   // A resident (implicit vmcnt(0) drain); ONLY barrier until stats flush

  for (int s = 0; s < 4; s++) {
    int pt0 = (pairidx * 4 + s) * 128;
    int b = pt0 >> 13;
    // per-thread argmin combine for this thread's OWN 2 B-rows (j=0,1)
    int gidx[2];
#pragma unroll
    for (int j = 0; j < 2; j++) {
      int p = pt0 + wp + j * 16 + lr;
      float bd = 3.0e38f; int bi = 0;
#pragma unroll
      for (int qc = 0; qc < 8; qc++) {
        float2 c = cand[(size_t)qc * 65536 + p];
        if (c.x < bd) { bd = c.x; bi = __float_as_int(c.y); }  // strict <: lower chunk wins ties
      }
      gidx[j] = bi;
    }
    floatx4 zero = {0.f, 0.f, 0.f, 0.f};
    floatx4 acc[4][2];
#pragma unroll
    for (int i = 0; i < 4; i++)
#pragma unroll
      for (int j = 0; j < 2; j++) acc[i][j] = zero;

#pragma unroll
    for (int step = 0; step < 6; step++) {   // k0 = step*64
      short8 bf[2][2];
#pragma unroll
      for (int ks = 0; ks < 2; ks++) {
#pragma unroll
        for (int j = 0; j < 2; j++) {
          int kk = ks * 32 + lq * 8;
          if (step < 2) {
            int p = pt0 + wp + j * 16 + lr;
            bf[ks][j] = *(const short8*)(f1t + (size_t)p * 128 + step * 64 + kk);
          } else {
            bf[ks][j] = *(const short8*)(f2t + ((size_t)(b << 11) + gidx[j]) * 256 +
                                         (step * 64 - 128) + kk);
          }
        }
      }
#pragma unroll
      for (int ks = 0; ks < 2; ks++) {
        short8 af[4];
#pragma unroll
        for (int i = 0; i < 4; i++) {
          int row = wrow + i * 16 + lr;
          af[i] = *(const short8*)&Aw[row * 384 + (((step * 8 + (ks << 2) + lq) ^ (lr & 7)) << 3)];
        }
#pragma unroll
        for (int i = 0; i < 4; i++)
#pragma unroll
          for (int j = 0; j < 2; j++)
            acc[i][j] = __builtin_amdgcn_mfma_f32_16x16x32_bf16(af[i], bf[ks][j], acc[i][j], 0, 0, 0);
      }
    }

    // y0 stores + register stats accumulation (no LDS, no barrier)
#pragma unroll
    for (int i = 0; i < 4; i++) {
#pragma unroll
      for (int j = 0; j < 2; j++) {
        int o = o0 + wrow + i * 16 + lq * 4;
        int p = pt0 + wp + j * 16 + lr;
        uint2 pk;
        pk.x = (u32)f2b(acc[i][j][0]) | ((u32)f2b(acc[i][j][1]) << 16);
        pk.y = (u32)f2b(acc[i][j][2]) | ((u32)f2b(acc[i][j][3]) << 16);
        *(uint2*)&y0[(size_t)p * 256 + o] = pk;
      }
#pragma unroll
      for (int r = 0; r < 4; r++) {
        float v0 = acc[i][0][r], v1 = acc[i][1][r];
        sa[i][r] += v0 + v1;
        qa[i][r] += v0 * v0 + v1 * v1;
      }
    }
  }

  // ---- stats flush: shfl-reduce over lr, LDS-combine across p-waves, one global atomic ----
#pragma unroll
  for (int i = 0; i < 4; i++)
#pragma unroll
    for (int r = 0; r < 4; r++)
#pragma unroll
      for (int m = 8; m >= 1; m >>= 1) {
        sa[i][r] += __shfl_xor(sa[i][r], m);
        qa[i][r] += __shfl_xor(qa[i][r], m);
      }
  __syncthreads();                  // all waves done reading Aw -> safe to alias
  float* red = (float*)Aw;          // 256 floats
  if (t < 256) red[t] = 0.f;
  __syncthreads();
  if (lr == 0) {
#pragma unroll
    for (int i = 0; i < 4; i++)
#pragma unroll
      for (int r = 0; r < 4; r++) {
        int o = wrow + i * 16 + lq * 4 + r;     // local channel [0,128)
        atomicAdd(&red[o], sa[i][r]);
        atomicAdd(&red[128 + o], qa[i][r]);
      }
  }
  __syncthreads();
  if (t < 128) {
    atomicAdd(&sum0[o0 + t], red[t]);
    atomicAdd(&sq0[o0 + t], red[128 + t]);
  }
}

// ---------------- GEMM2: A-resident (128o x 256k), stream 2x 256p tiles, fused BN0 + stats1 ----------------
// (unchanged from r5 — passing; gets the streaming treatment next round once gemm1 validates it)
__global__ __launch_bounds__(512, 2) void gemm2_k(const u16* __restrict__ w1b, const u16* __restrict__ y0,
                                                  const float* __restrict__ sum0, const float* __restrict__ sq0,
                                                  const float* __restrict__ gamma0, const float* __restrict__ beta0,
                                                  float* __restrict__ sum1, float* __restrict__ sq1,
                                                  u16* __restrict__ y1) {
  __shared__ u16 Aw[128 * 256];     // 64KB resident weights (o-half)
  __shared__ u16 Bs[2][256 * 64];   // 2x32KB dbuf, reg-staged with BN0 transform
  __shared__ float ssc[256], ssh[256];
  int t = threadIdx.x;
  int bid = blockIdx.x;
  int ohalf = (bid >> 3) & 1;
  int pairidx = (bid & 7) | ((bid >> 4) << 3);
  int o0 = ohalf * 128;
  int lane = t & 63, wave = t >> 6;
  int wrow = (wave >> 2) * 64;      // o within half
  int wp = (wave & 3) * 64;         // p-offset (4 groups of 64)
  int lr = lane & 15, lq = lane >> 4;
  if (t < 256) {                    // fused bnparam0
    float mean = sum0[t] * (1.f / 65536.f);
    float var = fmaxf(sq0[t] * (1.f / 65536.f) - mean * mean, 0.f);
    float r = rsqrtf(var + 1e-5f);
    float sc = gamma0[t] * r;
    ssc[t] = sc;
    ssh[t] = beta0[t] - mean * sc;
  }
  // ---- A-load: 8 glds16/thread ----
#pragma unroll
  for (int it = 0; it < 8; it++) {
    u32 off = (u32)it * 8192 + (u32)t * 16;      // byte offset (512B rows)
    int row = off >> 9;
    int c16 = (off & 511) >> 4;
    glds16(w1b + (size_t)(o0 + row) * 256 + ((c16 ^ (row & 7)) << 3),
           (char*)Aw + (size_t)it * 8192 + (size_t)wave * 1024);
  }

  // B staging ids: 4 per thread -> (row, phys chunk)
  int brow[4], bpc[4], bch[4];
#pragma unroll
  for (int i = 0; i < 4; i++) {
    int id = t + i * 512;
    brow[i] = id >> 3; bpc[i] = id & 7;
    bch[i] = (bpc[i] ^ (brow[i] & 7)) * 8;       // pre-swizzled logical source chunk
  }
  float sa[4][4], qa[4][4];
#pragma unroll
  for (int i = 0; i < 4; i++)
#pragma unroll
    for (int r = 0; r < 4; r++) { sa[i][r] = 0.f; qa[i][r] = 0.f; }

  __syncthreads();                  // ssc/ssh visible + A resident

  for (int s = 0; s < 2; s++) {
    int pt0 = (pairidx * 2 + s) * 256;
    uint4 rg[4];
    auto loadB = [&](int k0) {
#pragma unroll
      for (int i = 0; i < 4; i++)
        rg[i] = *(const uint4*)(y0 + (size_t)(pt0 + brow[i]) * 256 + k0 + bch[i]);
    };
    auto xformB = [&](int k0, int bufi) {
#pragma unroll
      for (int i = 0; i < 4; i++) {
        u32 rw[4] = {rg[i].x, rg[i].y, rg[i].z, rg[i].w};
        u32 ow[4];
#pragma unroll
        for (int w = 0; w < 4; w++) {
          int k = k0 + bch[i] + w * 2;
          float v0 = b2f((u16)(rw[w] & 0xffffu));
          float v1 = b2f((u16)(rw[w] >> 16));
          v0 = fmaxf(v0 * ssc[k] + ssh[k], 0.f);
          v1 = fmaxf(v1 * ssc[k + 1] + ssh[k + 1], 0.f);
          ow[w] = (u32)f2b(v0) | ((u32)f2b(v1) << 16);
        }
        uint4 ov; ov.x = ow[0]; ov.y = ow[1]; ov.z = ow[2]; ov.w = ow[3];
        *(uint4*)&Bs[bufi][brow[i] * 64 + bpc[i] * 8] = ov;   // contiguous 1KB/wave-op
      }
    };
    floatx4 zero = {0.f, 0.f, 0.f, 0.f};
    floatx4 acc[4][4];
#pragma unroll
    for (int i = 0; i < 4; i++)
#pragma unroll
      for (int j = 0; j < 4; j++) acc[i][j] = zero;
    auto compute = [&](int k0, int bufi) {
#pragma unroll
      for (int ks = 0; ks < 2; ks++) {
        short8 af[4], bf[4];
#pragma unroll
        for (int i = 0; i < 4; i++) {
          int row = wrow + i * 16 + lr;
          af[i] = *(const short8*)&Aw[row * 256 + ((((k0 >> 3) + (ks << 2) + lq) ^ (lr & 7)) << 3)];
        }
#pragma unroll
        for (int j = 0; j < 4; j++) {
          int row = wp + j * 16 + lr;
          bf[j] = *(const short8*)&Bs[bufi][row * 64 + ((((ks << 2) | lq) ^ (lr & 7)) << 3)];
        }
#pragma unroll
        for (int i = 0; i < 4; i++)
#pragma unroll
          for (int j = 0; j < 4; j++)
            acc[i][j] = __builtin_amdgcn_mfma_f32_16x16x32_bf16(af[i], bf[j], acc[i][j], 0, 0, 0);
      }
    };

    loadB(0);
    xformB(0, 0);
    __syncthreads();              // buf0 visible
#pragma unroll
    for (int k0i = 0; k0i < 4; k0i++) {
      if (k0i < 3) loadB((k0i + 1) * 64);        // issue early; regs used after compute
      compute(k0i * 64, k0i & 1);
      __syncthreads();
      if (k0i < 3) {
        xformB((k0i + 1) * 64, (k0i + 1) & 1);
        __syncthreads();
      }
    }
    // y1 stores + reg stats
#pragma unroll
    for (int i = 0; i < 4; i++) {
#pragma unroll
      for (int j = 0; j < 4; j++) {
        int o = o0 + wrow + i * 16 + lq * 4;
        int p = pt0 + wp + j * 16 + lr;
        uint2 pk;
        pk.x = (u32)f2b(acc[i][j][0]) | ((u32)f2b(acc[i][j][1]) << 16);
        pk.y = (u32)f2b(acc[i][j][2]) | ((u32)f2b(acc[i][j][3]) << 16);
        *(uint2*)&y1[(size_t)p * 256 + o] = pk;
      }
#pragma unroll
      for (int r = 0; r < 4; r++) {
        float v0 = acc[i][0][r], v1 = acc[i][1][r], v2 = acc[i][2][r], v3 = acc[i][3][r];
        sa[i][r] += v0 + v1 + v2 + v3;
        qa[i][r] += v0 * v0 + v1 * v1 + v2 * v2 + v3 * v3;
      }
    }
  }

#pragma unroll
  for (int i = 0; i < 4; i++)
#pragma unroll
    for (int r = 0; r < 4; r++)
#pragma unroll
      for (int m = 8; m >= 1; m >>= 1) {
        sa[i][r] += __shfl_xor(sa[i][r], m);
        qa[i][r] += __shfl_xor(qa[i][r], m);
      }
  __syncthreads();
  float* red = (float*)&Bs[0][0];
  if (t < 256) red[t] = 0.f;
  __syncthreads();
  if (lr == 0) {
#pragma unroll
    for (int i = 0; i < 4; i++)
#pragma unroll
      for (int r = 0; r < 4; r++) {
        int o = wrow + i * 16 + lq * 4 + r;
        atomicAdd(&red[o], sa[i][r]);
        atomicAdd(&red[128 + o], qa[i][r]);
      }
  }
  __syncthreads();
  if (t < 128) {
    atomicAdd(&sum1[o0 + t], red[t]);
    atomicAdd(&sq1[o0 + t], red[128 + t]);
  }
}

// ---------------- finalize: fused BN1 params + BN1+ReLU + transpose -> [b][o][n] fp32 ----------------
__global__ void finalize_k(const u16* __restrict__ y1, const float* __restrict__ sum1,
                           const float* __restrict__ sq1, const float* __restrict__ gamma1,
                           const float* __restrict__ beta1, float* __restrict__ out) {
  __shared__ float tile[64][65];
  __shared__ float fs[64], fh[64];
  int b = blockIdx.z, o0 = blockIdx.y * 64, n0 = blockIdx.x * 64;
  int t = threadIdx.x;
  if (t < 64) {
    int o = o0 + t;
    float mean = sum1[o] * (1.f / 65536.f);
    float var = fmaxf(sq1[o] * (1.f / 65536.f) - mean * mean, 0.f);
    float r = rsqrtf(var + 1e-5f);
    float sc = gamma1[o] * r;
    fs[t] = sc;
    fh[t] = beta1[o] - mean * sc;
  }
  __syncthreads();
  int pl = t >> 2, ch = (t & 3) * 16;
  const u16* src = y1 + ((size_t)(b * 8192 + n0 + pl)) * 256 + o0 + ch;
  uint4 r0 = *(const uint4*)src;
  uint4 r1 = *(const uint4*)(src + 8);
  u16 hv[16];
  *(uint4*)&hv[0] = r0;
  *(uint4*)&hv[8] = r1;
#pragma unroll
  for (int e = 0; e < 16; e++) {
    float v = b2f(hv[e]) * fs[ch + e] + fh[ch + e];
    tile[pl][ch + e] = fmaxf(v, 0.f);
  }
  __syncthreads();
  int ol = t >> 2, nch = (t & 3) * 16;
  float* dst = out + ((size_t)(b * 256 + o0 + ol)) * 8192 + n0 + nch;
#pragma unroll
  for (int j = 0; j < 16; j += 4) {
    float4 v = make_float4(tile[nch + j][ol], tile[nch + j + 1][ol],
                           tile[nch + j + 2][ol], tile[nch + j + 3][ol]);
    *(float4*)(dst + j) = v;
  }
}

extern "C" void kernel_launch(void* const* d_in, const int* in_sizes, int n_in,
                              void* d_out, int out_size, void* d_ws, size_t ws_size,
                              hipStream_t stream) {
  const float* xyz1      = (const float*)d_in[0];
  const float* xyz2      = (const float*)d_in[1];
  const float* features1 = (const float*)d_in[2];
  const float* features2 = (const float*)d_in[3];
  const float* conv_w0   = (const float*)d_in[4];
  const float* gamma0    = (const float*)d_in[5];
  const float* beta0     = (const float*)d_in[6];
  const float* conv_w1   = (const float*)d_in[7];
  const float* gamma1    = (const float*)d_in[8];
  const float* beta1     = (const float*)d_in[9];
  float* out = (float*)d_out;

  char* ws = (char*)d_ws;
  size_t off = 0;
  auto alloc = [&](size_t bytes) {
    char* p = ws + off;
    off = (off + bytes + 4095) & ~(size_t)4095;
    return p;
  };
  float*  sums = (float*)alloc(4 * 256 * 4);            // sum0, sq0, sum1, sq1
  u16*    w0b  = (u16*)alloc(256 * 384 * 2);
  u16*    w1b  = (u16*)alloc(256 * 256 * 2);
  float2* cand = (float2*)alloc((size_t)8 * 65536 * 8); // 4MB
  u16*    f1t  = (u16*)alloc((size_t)65536 * 128 * 2);
  u16*    f2t  = (u16*)alloc((size_t)16384 * 256 * 2);
  u16*    y0   = (u16*)alloc((size_t)65536 * 256 * 2);
  u16*    y1   = (u16*)alloc((size_t)65536 * 256 * 2);

  prep_all_k<<<dim3(4224), 256, 0, stream>>>(xyz1, xyz2, cand, features1, f1t,
                                             features2, f2t, conv_w0, w0b, conv_w1, w1b, sums);
  gemm1_k<<<dim3(256), 512, 0, stream>>>(w0b, f1t, f2t, cand, sums + 0, sums + 256, y0);
  gemm2_k<<<dim3(256), 512, 0, stream>>>(w1b, y0, sums + 0, sums + 256, gamma0, beta0,
                                         sums + 512, sums + 768, y1);
  finalize_k<<<dim3(128, 4, 8), 256, 0, stream>>>(y1, sums + 512, sums + 768, gamma1, beta1, out);
}

// Round 7
// 247.081 us; speedup vs baseline: 1.0957x; 1.0957x over previous
//
#include <hip/hip_runtime.h>
#include <stdint.h>

typedef unsigned short u16;
typedef unsigned int u32;
typedef __attribute__((ext_vector_type(8))) short short8;
typedef __attribute__((ext_vector_type(4))) float floatx4;

__device__ __forceinline__ u16 f2b(float f) {
  union { float f; u32 u; } c; c.f = f;
  u32 u = c.u;
  u += 0x7fffu + ((u >> 16) & 1u);
  return (u16)(u >> 16);
}
__device__ __forceinline__ float b2f(u16 h) {
  union { u32 u; float f; } c; c.u = ((u32)h) << 16;
  return c.f;
}

// async global->LDS, 16B per lane; LDS dest is wave-uniform base + lane*16
__device__ __forceinline__ void glds16(const void* g, void* l) {
  __builtin_amdgcn_global_load_lds((__attribute__((address_space(1))) void*)g,
                                   (__attribute__((address_space(3))) void*)l, 16, 0, 0);
}

// ---------------- mega-prep: argmin parts | transposes | weight casts | zero sums ----------------
__global__ void prep_all_k(const float* __restrict__ xyz1, const float* __restrict__ xyz2,
                           float2* __restrict__ cand,
                           const float* __restrict__ f1, u16* __restrict__ f1t,
                           const float* __restrict__ f2, u16* __restrict__ f2t,
                           const float* __restrict__ w0, u16* __restrict__ w0b,
                           const float* __restrict__ w1, u16* __restrict__ w1b,
                           float* __restrict__ sums) {
  __shared__ __align__(16) char smem[9216];
  int blk = blockIdx.x, t = threadIdx.x;
  if (blk < 512) {
    float4* s2 = (float4*)smem;
    int nq = blk & 7, mq = (blk >> 3) & 7, b = blk >> 6;
    const float* x2 = xyz2 + ((size_t)b * 2048 + mq * 256) * 3;
    s2[t] = make_float4(x2[t * 3], x2[t * 3 + 1], x2[t * 3 + 2], 0.f);
    __syncthreads();
    int n0 = nq * 1024 + t;
    float px[4], py[4], pz[4];
#pragma unroll
    for (int q = 0; q < 4; q++) {
      const float* p1 = xyz1 + ((size_t)b * 8192 + n0 + q * 256) * 3;
      px[q] = p1[0]; py[q] = p1[1]; pz[q] = p1[2];
    }
    float best[4] = {3.0e38f, 3.0e38f, 3.0e38f, 3.0e38f};
    int bi[4] = {0, 0, 0, 0};
#pragma unroll 4
    for (int m = 0; m < 256; m++) {
      float4 qq = s2[m];
#pragma unroll
      for (int q = 0; q < 4; q++) {
        float dx = px[q] - qq.x, dy = py[q] - qq.y, dz = pz[q] - qq.z;
        float d = fmaf(dz, dz, fmaf(dy, dy, dx * dx));  // EXACT contraction from passing rounds
        bool c = d < best[q];
        best[q] = c ? d : best[q];
        bi[q] = c ? m : bi[q];
      }
    }
#pragma unroll
    for (int q = 0; q < 4; q++) {
      int n = n0 + q * 256;
      cand[(size_t)mq * 65536 + (size_t)b * 8192 + n] =
          make_float2(best[q], __int_as_float(mq * 256 + bi[q]));
    }
  } else if (blk < 3584) {
    const float* in; u16* out; int C, N, bx, by, bz;
    if (blk < 2560) { int rel = blk - 512;  in = f1; out = f1t; C = 128; N = 8192; bx = rel & 127; by = (rel >> 7) & 1; bz = rel >> 8; }
    else            { int rel = blk - 2560; in = f2; out = f2t; C = 256; N = 2048; bx = rel & 31;  by = (rel >> 5) & 3; bz = rel >> 7; }
    u16 (*tile)[72] = (u16(*)[72])smem;
    int c0 = by * 64, n0 = bx * 64;
    const float* src = in + ((size_t)bz * C + c0) * N + n0;
#pragma unroll
    for (int i = 0; i < 4; i++) {
      int id = t + i * 256;
      int c = id >> 4, nq = (id & 15) * 4;
      float4 v = *(const float4*)(src + (size_t)c * N + nq);
      tile[nq + 0][c] = f2b(v.x);
      tile[nq + 1][c] = f2b(v.y);
      tile[nq + 2][c] = f2b(v.z);
      tile[nq + 3][c] = f2b(v.w);
    }
    __syncthreads();
    int n = t >> 2, ch = (t & 3) * 16;
    u16* dst = out + ((size_t)bz * N + n0 + n) * C + c0 + ch;
    *(uint4*)dst = *(const uint4*)&tile[n][ch];
    *(uint4*)(dst + 8) = *(const uint4*)&tile[n][ch + 8];
  } else {
    int rel = blk - 3584;
    int i = rel * 256 + t;
    if (rel < 384) w0b[i] = f2b(w0[i]);
    else { int j = i - 98304; w1b[j] = f2b(w1[j]); }
    if (rel < 4) sums[i] = 0.f;
  }
}

// ---------------- GEMM1: A in REGISTERS (48x16B from L2-resident w0b), B via glds16 dbuf ----------------
// 4 waves/block, 128o x 64p tile, 4 p-tiles per block. Grid 512 = 2 blocks/CU.
// K-loop: only 4 ds_read_b128 per wave per K-step (was 12) -> breaks the LDS-throughput wall.
// r5-proven sync skeleton: stage(next) -> compute(cur) -> __syncthreads (drains vmcnt).
__global__ __launch_bounds__(256, 2) void gemm1_k(const u16* __restrict__ w0b, const u16* __restrict__ f1t,
                                                  const u16* __restrict__ f2t, const float2* __restrict__ cand,
                                                  float* __restrict__ sum0, float* __restrict__ sq0,
                                                  u16* __restrict__ y0) {
  __shared__ u16 Bs[2][64 * 64];   // 2x8KB dbuf, XOR swizzle: phys 16B-chunk = logical ^ (row&7)
  __shared__ float red[256];        // persistent per-block stats: sum[0..127], sq[128..255]
  int t = threadIdx.x;
  int bid = blockIdx.x;
  int ohalf = (bid >> 3) & 1;
  int pairidx = (bid & 7) | ((bid >> 4) << 3);   // [0,256); (bid, bid+8) share p-range on same XCD
  int o0 = ohalf * 128;
  int lane = t & 63, wave = t >> 6;   // 4 waves
  int wrow = (wave >> 1) * 64;        // o-group within half
  int wp = (wave & 1) * 32;           // p-group
  int lr = lane & 15, lq = lane >> 4;
  int srow = lane >> 3;
  int sch = ((lane & 7) ^ srow) * 8;

  red[t] = 0.f;                       // barrier before first use comes from the K-loop

  // ---- A -> registers: areg[i][kf] = w0b[o0+wrow+i*16+lr][kf*32 + lq*8 ..+7] ----
  short8 areg[4][12];
#pragma unroll
  for (int i = 0; i < 4; i++) {
    const u16* wr = w0b + (size_t)(o0 + wrow + i * 16 + lr) * 384 + lq * 8;
#pragma unroll
    for (int kf = 0; kf < 12; kf++)
      areg[i][kf] = *(const short8*)(wr + kf * 32);
  }

  for (int s = 0; s < 4; s++) {
    int pt0 = (pairidx * 4 + s) * 64;
    size_t bb = (size_t)((pt0 >> 13) << 11);
    // per-thread argmin combine for this thread's 2 staged B-rows
    int gidx[2];
#pragma unroll
    for (int i = 0; i < 2; i++) {
      int p = pt0 + (wave * 2 + i) * 8 + srow;
      float bd = 3.0e38f; int bi = 0;
#pragma unroll
      for (int qc = 0; qc < 8; qc++) {
        float2 c = cand[(size_t)qc * 65536 + p];
        if (c.x < bd) { bd = c.x; bi = __float_as_int(c.y); }  // strict <: lower chunk wins ties
      }
      gidx[i] = bi;
    }
    floatx4 zero = {0.f, 0.f, 0.f, 0.f};
    floatx4 acc[4][2];
#pragma unroll
    for (int i = 0; i < 4; i++)
#pragma unroll
      for (int j = 0; j < 2; j++) acc[i][j] = zero;

    auto stageB = [&](int step, int bufi) {
#pragma unroll
      for (int i = 0; i < 2; i++) {
        int row = (wave * 2 + i) * 8 + srow;   // 0..63
        const u16* src;
        if (step < 2) src = f1t + (size_t)(pt0 + row) * 128 + step * 64 + sch;
        else          src = f2t + (bb + gidx[i]) * 256 + (step * 64 - 128) + sch;
        glds16(src, &Bs[bufi][(wave * 2 + i) * 512]);
      }
    };

    stageB(0, 0);
    __syncthreads();                 // B0 ready (implicit vmcnt drain); also covers red[] init at s=0
#pragma unroll
    for (int step = 0; step < 6; step++) {
      if (step < 5) stageB(step + 1, (step + 1) & 1);
#pragma unroll
      for (int ks = 0; ks < 2; ks++) {
        short8 bf[2];
#pragma unroll
        for (int j = 0; j < 2; j++)
          bf[j] = *(const short8*)&Bs[step & 1][(wp + j * 16 + lr) * 64 +
                                               ((((ks << 2) | lq) ^ (lr & 7)) << 3)];
        int kf = step * 2 + ks;
#pragma unroll
        for (int i = 0; i < 4; i++)
#pragma unroll
          for (int j = 0; j < 2; j++)
            acc[i][j] = __builtin_amdgcn_mfma_f32_16x16x32_bf16(areg[i][kf], bf[j], acc[i][j], 0, 0, 0);
      }
      __syncthreads();               // drains vmcnt: next buf ready; orders buffer reuse
    }

    // epilogue: y0 stores + stats flush into persistent LDS red[]
#pragma unroll
    for (int i = 0; i < 4; i++) {
#pragma unroll
      for (int j = 0; j < 2; j++) {
        int o = o0 + wrow + i * 16 + lq * 4;
        int p = pt0 + wp + j * 16 + lr;
        uint2 pk;
        pk.x = (u32)f2b(acc[i][j][0]) | ((u32)f2b(acc[i][j][1]) << 16);
        pk.y = (u32)f2b(acc[i][j][2]) | ((u32)f2b(acc[i][j][3]) << 16);
        *(uint2*)&y0[(size_t)p * 256 + o] = pk;
      }
#pragma unroll
      for (int r = 0; r < 4; r++) {
        float sv = acc[i][0][r] + acc[i][1][r];
        float qv = acc[i][0][r] * acc[i][0][r] + acc[i][1][r] * acc[i][1][r];
#pragma unroll
        for (int m = 8; m >= 1; m >>= 1) { sv += __shfl_xor(sv, m); qv += __shfl_xor(qv, m); }
        if (lr == 0) {
          int o = wrow + i * 16 + lq * 4 + r;   // local channel [0,128)
          atomicAdd(&red[o], sv);
          atomicAdd(&red[128 + o], qv);
        }
      }
    }
  }

  __syncthreads();
  if (t < 128) {
    atomicAdd(&sum0[o0 + t], red[t]);
    atomicAdd(&sq0[o0 + t], red[128 + t]);
  }
}

// ---------------- GEMM2: A-resident (128o x 256k), stream 2x 256p tiles, fused BN0 + stats1 ----------------
// (exact r5 code — passing at ~<48us; gets the A-in-reg treatment once gemm1 validates it)
__global__ __launch_bounds__(512, 2) void gemm2_k(const u16* __restrict__ w1b, const u16* __restrict__ y0,
                                                  const float* __restrict__ sum0, const float* __restrict__ sq0,
                                                  const float* __restrict__ gamma0, const float* __restrict__ beta0,
                                                  float* __restrict__ sum1, float* __restrict__ sq1,
                                                  u16* __restrict__ y1) {
  __shared__ u16 Aw[128 * 256];     // 64KB resident weights (o-half)
  __shared__ u16 Bs[2][256 * 64];   // 2x32KB dbuf, reg-staged with BN0 transform
  __shared__ float ssc[256], ssh[256];
  int t = threadIdx.x;
  int bid = blockIdx.x;
  int ohalf = (bid >> 3) & 1;
  int pairidx = (bid & 7) | ((bid >> 4) << 3);
  int o0 = ohalf * 128;
  int lane = t & 63, wave = t >> 6;
  int wrow = (wave >> 2) * 64;      // o within half
  int wp = (wave & 3) * 64;         // p-offset (4 groups of 64)
  int lr = lane & 15, lq = lane >> 4;
  if (t < 256) {                    // fused bnparam0
    float mean = sum0[t] * (1.f / 65536.f);
    float var = fmaxf(sq0[t] * (1.f / 65536.f) - mean * mean, 0.f);
    float r = rsqrtf(var + 1e-5f);
    float sc = gamma0[t] * r;
    ssc[t] = sc;
    ssh[t] = beta0[t] - mean * sc;
  }
  // ---- A-load: 8 glds16/thread ----
#pragma unroll
  for (int it = 0; it < 8; it++) {
    u32 off = (u32)it * 8192 + (u32)t * 16;      // byte offset (512B rows)
    int row = off >> 9;
    int c16 = (off & 511) >> 4;
    glds16(w1b + (size_t)(o0 + row) * 256 + ((c16 ^ (row & 7)) << 3),
           (char*)Aw + (size_t)it * 8192 + (size_t)wave * 1024);
  }

  // B staging ids: 4 per thread -> (row, phys chunk)
  int brow[4], bpc[4], bch[4];
#pragma unroll
  for (int i = 0; i < 4; i++) {
    int id = t + i * 512;
    brow[i] = id >> 3; bpc[i] = id & 7;
    bch[i] = (bpc[i] ^ (brow[i] & 7)) * 8;       // pre-swizzled logical source chunk
  }
  float sa[4][4], qa[4][4];
#pragma unroll
  for (int i = 0; i < 4; i++)
#pragma unroll
    for (int r = 0; r < 4; r++) { sa[i][r] = 0.f; qa[i][r] = 0.f; }

  __syncthreads();                  // ssc/ssh visible + A resident

  for (int s = 0; s < 2; s++) {
    int pt0 = (pairidx * 2 + s) * 256;
    uint4 rg[4];
    auto loadB = [&](int k0) {
#pragma unroll
      for (int i = 0; i < 4; i++)
        rg[i] = *(const uint4*)(y0 + (size_t)(pt0 + brow[i]) * 256 + k0 + bch[i]);
    };
    auto xformB = [&](int k0, int bufi) {
#pragma unroll
      for (int i = 0; i < 4; i++) {
        u32 rw[4] = {rg[i].x, rg[i].y, rg[i].z, rg[i].w};
        u32 ow[4];
#pragma unroll
        for (int w = 0; w < 4; w++) {
          int k = k0 + bch[i] + w * 2;
          float v0 = b2f((u16)(rw[w] & 0xffffu));
          float v1 = b2f((u16)(rw[w] >> 16));
          v0 = fmaxf(v0 * ssc[k] + ssh[k], 0.f);
          v1 = fmaxf(v1 * ssc[k + 1] + ssh[k + 1], 0.f);
          ow[w] = (u32)f2b(v0) | ((u32)f2b(v1) << 16);
        }
        uint4 ov; ov.x = ow[0]; ov.y = ow[1]; ov.z = ow[2]; ov.w = ow[3];
        *(uint4*)&Bs[bufi][brow[i] * 64 + bpc[i] * 8] = ov;   // contiguous 1KB/wave-op
      }
    };
    floatx4 zero = {0.f, 0.f, 0.f, 0.f};
    floatx4 acc[4][4];
#pragma unroll
    for (int i = 0; i < 4; i++)
#pragma unroll
      for (int j = 0; j < 4; j++) acc[i][j] = zero;
    auto compute = [&](int k0, int bufi) {
#pragma unroll
      for (int ks = 0; ks < 2; ks++) {
        short8 af[4], bf[4];
#pragma unroll
        for (int i = 0; i < 4; i++) {
          int row = wrow + i * 16 + lr;
          af[i] = *(const short8*)&Aw[row * 256 + ((((k0 >> 3) + (ks << 2) + lq) ^ (lr & 7)) << 3)];
        }
#pragma unroll
        for (int j = 0; j < 4; j++) {
          int row = wp + j * 16 + lr;
          bf[j] = *(const short8*)&Bs[bufi][row * 64 + ((((ks << 2) | lq) ^ (lr & 7)) << 3)];
        }
#pragma unroll
        for (int i = 0; i < 4; i++)
#pragma unroll
          for (int j = 0; j < 4; j++)
            acc[i][j] = __builtin_amdgcn_mfma_f32_16x16x32_bf16(af[i], bf[j], acc[i][j], 0, 0, 0);
      }
    };

    loadB(0);
    xformB(0, 0);
    __syncthreads();              // buf0 visible
#pragma unroll
    for (int k0i = 0; k0i < 4; k0i++) {
      if (k0i < 3) loadB((k0i + 1) * 64);        // issue early; regs used after compute
      compute(k0i * 64, k0i & 1);
      __syncthreads();
      if (k0i < 3) {
        xformB((k0i + 1) * 64, (k0i + 1) & 1);
        __syncthreads();
      }
    }
    // y1 stores + reg stats
#pragma unroll
    for (int i = 0; i < 4; i++) {
#pragma unroll
      for (int j = 0; j < 4; j++) {
        int o = o0 + wrow + i * 16 + lq * 4;
        int p = pt0 + wp + j * 16 + lr;
        uint2 pk;
        pk.x = (u32)f2b(acc[i][j][0]) | ((u32)f2b(acc[i][j][1]) << 16);
        pk.y = (u32)f2b(acc[i][j][2]) | ((u32)f2b(acc[i][j][3]) << 16);
        *(uint2*)&y1[(size_t)p * 256 + o] = pk;
      }
#pragma unroll
      for (int r = 0; r < 4; r++) {
        float v0 = acc[i][0][r], v1 = acc[i][1][r], v2 = acc[i][2][r], v3 = acc[i][3][r];
        sa[i][r] += v0 + v1 + v2 + v3;
        qa[i][r] += v0 * v0 + v1 * v1 + v2 * v2 + v3 * v3;
      }
    }
  }

#pragma unroll
  for (int i = 0; i < 4; i++)
#pragma unroll
    for (int r = 0; r < 4; r++)
#pragma unroll
      for (int m = 8; m >= 1; m >>= 1) {
        sa[i][r] += __shfl_xor(sa[i][r], m);
        qa[i][r] += __shfl_xor(qa[i][r], m);
      }
  __syncthreads();
  float* red = (float*)&Bs[0][0];
  if (t < 256) red[t] = 0.f;
  __syncthreads();
  if (lr == 0) {
#pragma unroll
    for (int i = 0; i < 4; i++)
#pragma unroll
      for (int r = 0; r < 4; r++) {
        int o = wrow + i * 16 + lq * 4 + r;
        atomicAdd(&red[o], sa[i][r]);
        atomicAdd(&red[128 + o], qa[i][r]);
      }
  }
  __syncthreads();
  if (t < 128) {
    atomicAdd(&sum1[o0 + t], red[t]);
    atomicAdd(&sq1[o0 + t], red[128 + t]);
  }
}

// ---------------- finalize: fused BN1 params + BN1+ReLU + transpose -> [b][o][n] fp32 ----------------
__global__ void finalize_k(const u16* __restrict__ y1, const float* __restrict__ sum1,
                           const float* __restrict__ sq1, const float* __restrict__ gamma1,
                           const float* __restrict__ beta1, float* __restrict__ out) {
  __shared__ float tile[64][65];
  __shared__ float fs[64], fh[64];
  int b = blockIdx.z, o0 = blockIdx.y * 64, n0 = blockIdx.x * 64;
  int t = threadIdx.x;
  if (t < 64) {
    int o = o0 + t;
    float mean = sum1[o] * (1.f / 65536.f);
    float var = fmaxf(sq1[o] * (1.f / 65536.f) - mean * mean, 0.f);
    float r = rsqrtf(var + 1e-5f);
    float sc = gamma1[o] * r;
    fs[t] = sc;
    fh[t] = beta1[o] - mean * sc;
  }
  __syncthreads();
  int pl = t >> 2, ch = (t & 3) * 16;
  const u16* src = y1 + ((size_t)(b * 8192 + n0 + pl)) * 256 + o0 + ch;
  uint4 r0 = *(const uint4*)src;
  uint4 r1 = *(const uint4*)(src + 8);
  u16 hv[16];
  *(uint4*)&hv[0] = r0;
  *(uint4*)&hv[8] = r1;
#pragma unroll
  for (int e = 0; e < 16; e++) {
    float v = b2f(hv[e]) * fs[ch + e] + fh[ch + e];
    tile[pl][ch + e] = fmaxf(v, 0.f);
  }
  __syncthreads();
  int ol = t >> 2, nch = (t & 3) * 16;
  float* dst = out + ((size_t)(b * 256 + o0 + ol)) * 8192 + n0 + nch;
#pragma unroll
  for (int j = 0; j < 16; j += 4) {
    float4 v = make_float4(tile[nch + j][ol], tile[nch + j + 1][ol],
                           tile[nch + j + 2][ol], tile[nch + j + 3][ol]);
    *(float4*)(dst + j) = v;
  }
}

extern "C" void kernel_launch(void* const* d_in, const int* in_sizes, int n_in,
                              void* d_out, int out_size, void* d_ws, size_t ws_size,
                              hipStream_t stream) {
  const float* xyz1      = (const float*)d_in[0];
  const float* xyz2      = (const float*)d_in[1];
  const float* features1 = (const float*)d_in[2];
  const float* features2 = (const float*)d_in[3];
  const float* conv_w0   = (const float*)d_in[4];
  const float* gamma0    = (const float*)d_in[5];
  const float* beta0     = (const float*)d_in[6];
  const float* conv_w1   = (const float*)d_in[7];
  const float* gamma1    = (const float*)d_in[8];
  const float* beta1     = (const float*)d_in[9];
  float* out = (float*)d_out;

  char* ws = (char*)d_ws;
  size_t off = 0;
  auto alloc = [&](size_t bytes) {
    char* p = ws + off;
    off = (off + bytes + 4095) & ~(size_t)4095;
    return p;
  };
  float*  sums = (float*)alloc(4 * 256 * 4);            // sum0, sq0, sum1, sq1
  u16*    w0b  = (u16*)alloc(256 * 384 * 2);
  u16*    w1b  = (u16*)alloc(256 * 256 * 2);
  float2* cand = (float2*)alloc((size_t)8 * 65536 * 8); // 4MB
  u16*    f1t  = (u16*)alloc((size_t)65536 * 128 * 2);
  u16*    f2t  = (u16*)alloc((size_t)16384 * 256 * 2);
  u16*    y0   = (u16*)alloc((size_t)65536 * 256 * 2);
  u16*    y1   = (u16*)alloc((size_t)65536 * 256 * 2);

  prep_all_k<<<dim3(4224), 256, 0, stream>>>(xyz1, xyz2, cand, features1, f1t,
                                             features2, f2t, conv_w0, w0b, conv_w1, w1b, sums);
  gemm1_k<<<dim3(512), 256, 0, stream>>>(w0b, f1t, f2t, cand, sums + 0, sums + 256, y0);
  gemm2_k<<<dim3(256), 512, 0, stream>>>(w1b, y0, sums + 0, sums + 256, gamma0, beta0,
                                         sums + 512, sums + 768, y1);
  finalize_k<<<dim3(128, 4, 8), 256, 0, stream>>>(y1, sums + 512, sums + 768, gamma1, beta1, out);
}

// Round 8
// 231.361 us; speedup vs baseline: 1.1702x; 1.0679x over previous
//
#include <hip/hip_runtime.h>
#include <stdint.h>

typedef unsigned short u16;
typedef unsigned int u32;
typedef __attribute__((ext_vector_type(8))) short short8;
typedef __attribute__((ext_vector_type(4))) float floatx4;

#define WVM4 asm volatile("s_waitcnt vmcnt(4)" ::: "memory")
#define WVM2 asm volatile("s_waitcnt vmcnt(2)" ::: "memory")
#define WVM0 asm volatile("s_waitcnt vmcnt(0)" ::: "memory")
#define SCHED0() __builtin_amdgcn_sched_barrier(0)
#define BAR() __builtin_amdgcn_s_barrier()

__device__ __forceinline__ u16 f2b(float f) {
  union { float f; u32 u; } c; c.f = f;
  u32 u = c.u;
  u += 0x7fffu + ((u >> 16) & 1u);
  return (u16)(u >> 16);
}
__device__ __forceinline__ float b2f(u16 h) {
  union { u32 u; float f; } c; c.u = ((u32)h) << 16;
  return c.f;
}

// async global->LDS, 16B per lane; LDS dest is wave-uniform base + lane*16
__device__ __forceinline__ void glds16(const void* g, void* l) {
  __builtin_amdgcn_global_load_lds((__attribute__((address_space(1))) void*)g,
                                   (__attribute__((address_space(3))) void*)l, 16, 0, 0);
}

// ---------------- mega-prep: argmin parts | transposes | weight casts | zero sums ----------------
__global__ void prep_all_k(const float* __restrict__ xyz1, const float* __restrict__ xyz2,
                           float2* __restrict__ cand,
                           const float* __restrict__ f1, u16* __restrict__ f1t,
                           const float* __restrict__ f2, u16* __restrict__ f2t,
                           const float* __restrict__ w0, u16* __restrict__ w0b,
                           const float* __restrict__ w1, u16* __restrict__ w1b,
                           float* __restrict__ sums) {
  __shared__ __align__(16) char smem[9216];
  int blk = blockIdx.x, t = threadIdx.x;
  if (blk < 512) {
    float4* s2 = (float4*)smem;
    int nq = blk & 7, mq = (blk >> 3) & 7, b = blk >> 6;
    const float* x2 = xyz2 + ((size_t)b * 2048 + mq * 256) * 3;
    s2[t] = make_float4(x2[t * 3], x2[t * 3 + 1], x2[t * 3 + 2], 0.f);
    __syncthreads();
    int n0 = nq * 1024 + t;
    float px[4], py[4], pz[4];
#pragma unroll
    for (int q = 0; q < 4; q++) {
      const float* p1 = xyz1 + ((size_t)b * 8192 + n0 + q * 256) * 3;
      px[q] = p1[0]; py[q] = p1[1]; pz[q] = p1[2];
    }
    float best[4] = {3.0e38f, 3.0e38f, 3.0e38f, 3.0e38f};
    int bi[4] = {0, 0, 0, 0};
#pragma unroll 4
    for (int m = 0; m < 256; m++) {
      float4 qq = s2[m];
#pragma unroll
      for (int q = 0; q < 4; q++) {
        float dx = px[q] - qq.x, dy = py[q] - qq.y, dz = pz[q] - qq.z;
        float d = fmaf(dz, dz, fmaf(dy, dy, dx * dx));  // EXACT contraction from passing rounds
        bool c = d < best[q];
        best[q] = c ? d : best[q];
        bi[q] = c ? m : bi[q];
      }
    }
#pragma unroll
    for (int q = 0; q < 4; q++) {
      int n = n0 + q * 256;
      cand[(size_t)mq * 65536 + (size_t)b * 8192 + n] =
          make_float2(best[q], __int_as_float(mq * 256 + bi[q]));
    }
  } else if (blk < 3584) {
    const float* in; u16* out; int C, N, bx, by, bz;
    if (blk < 2560) { int rel = blk - 512;  in = f1; out = f1t; C = 128; N = 8192; bx = rel & 127; by = (rel >> 7) & 1; bz = rel >> 8; }
    else            { int rel = blk - 2560; in = f2; out = f2t; C = 256; N = 2048; bx = rel & 31;  by = (rel >> 5) & 3; bz = rel >> 7; }
    u16 (*tile)[72] = (u16(*)[72])smem;
    int c0 = by * 64, n0 = bx * 64;
    const float* src = in + ((size_t)bz * C + c0) * N + n0;
#pragma unroll
    for (int i = 0; i < 4; i++) {
      int id = t + i * 256;
      int c = id >> 4, nq = (id & 15) * 4;
      float4 v = *(const float4*)(src + (size_t)c * N + nq);
      tile[nq + 0][c] = f2b(v.x);
      tile[nq + 1][c] = f2b(v.y);
      tile[nq + 2][c] = f2b(v.z);
      tile[nq + 3][c] = f2b(v.w);
    }
    __syncthreads();
    int n = t >> 2, ch = (t & 3) * 16;
    u16* dst = out + ((size_t)bz * N + n0 + n) * C + c0 + ch;
    *(uint4*)dst = *(const uint4*)&tile[n][ch];
    *(uint4*)(dst + 8) = *(const uint4*)&tile[n][ch + 8];
  } else {
    int rel = blk - 3584;
    int i = rel * 256 + t;
    if (rel < 384) w0b[i] = f2b(w0[i]);
    else { int j = i - 98304; w1b[j] = f2b(w1[j]); }
    if (rel < 4) sums[i] = 0.f;
  }
}

// ---------------- GEMM1: r5 A-resident structure + counted-vmcnt 3-buffer B pipeline (T3/T4) ----------------
// 24 global K-steps (4 p-tiles x 6). Uniform 2-glds16 stages, 3 LDS buffers, waits 4/4/.../4/2/0.
// Stores issued mid-pipeline are NEWER than any stage being waited on -> vmcnt(N) can only over-wait (safe).
__global__ __launch_bounds__(512, 1) void gemm1_k(const u16* __restrict__ w0b, const u16* __restrict__ f1t,
                                                  const u16* __restrict__ f2t, const float2* __restrict__ cand,
                                                  float* __restrict__ sum0, float* __restrict__ sq0,
                                                  u16* __restrict__ y0) {
  __shared__ u16 Aw[128 * 384];     // 96KB resident weights (o-half), XOR swizzle within 8-chunk groups
  __shared__ u16 Bs[3][128 * 64];   // 3x16KB pipeline buffers
  int t = threadIdx.x;
  int bid = blockIdx.x;
  int ohalf = (bid >> 3) & 1;
  int pairidx = (bid & 7) | ((bid >> 4) << 3);   // [0,128); o-pair on same XCD
  int o0 = ohalf * 128;
  int lane = t & 63, wave = t >> 6;              // 8 waves
  int wrow = (wave >> 2) * 64;                   // o-offset within half (2 o-groups)
  int wp = (wave & 3) * 32;                      // p-offset (4 p-groups)
  int lr = lane & 15, lq = lane >> 4;
  int srow = lane >> 3;
  int sch = ((lane & 7) ^ srow) * 8;

  // ---- A-load: 12 glds16/thread (linear LDS dest; per-lane source carries the swizzle) ----
#pragma unroll
  for (int it = 0; it < 12; it++) {
    u32 off = (u32)it * 8192 + (u32)t * 16;
    int row = off / 768;
    int c16 = (off - row * 768) >> 4;
    glds16(w0b + (size_t)(o0 + row) * 384 + ((c16 ^ (row & 7)) << 3),
           (char*)Aw + (size_t)it * 8192 + (size_t)wave * 1024);
  }

  // ---- argmin combine for ALL 4 p-tiles upfront (keeps vmcnt counts exact in the pipeline) ----
  int gidx[4][2];
#pragma unroll
  for (int s = 0; s < 4; s++) {
    int pt0 = (pairidx * 4 + s) * 128;
#pragma unroll
    for (int i = 0; i < 2; i++) {
      int p = pt0 + (wave * 2 + i) * 8 + srow;
      float bd = 3.0e38f; int bi = 0;
#pragma unroll
      for (int qc = 0; qc < 8; qc++) {
        float2 c = cand[(size_t)qc * 65536 + p];
        if (c.x < bd) { bd = c.x; bi = __float_as_int(c.y); }  // strict <: lower chunk wins ties
      }
      gidx[s][i] = bi;
    }
  }

  float sa[4][4], qa[4][4];
#pragma unroll
  for (int i = 0; i < 4; i++)
#pragma unroll
    for (int r = 0; r < 4; r++) { sa[i][r] = 0.f; qa[i][r] = 0.f; }

  __syncthreads();   // A resident; full vmcnt drain -> pipeline starts from count 0

  // stage for global step T (compile-time at every call site)
  auto stageT = [&](int T) {
    int s2 = T / 6, k = T % 6, buf = T % 3;
    int pt0s = (pairidx * 4 + s2) * 128;
    size_t bb = (size_t)((pt0s >> 13) << 11);
#pragma unroll
    for (int i = 0; i < 2; i++) {
      int row = (wave * 2 + i) * 8 + srow;
      const u16* src;
      if (k < 2) src = f1t + (size_t)(pt0s + row) * 128 + k * 64 + sch;
      else       src = f2t + (bb + gidx[s2][i]) * 256 + (k * 64 - 128) + sch;
      glds16(src, &Bs[buf][(wave * 2 + i) * 512]);
    }
  };

  // prologue: 3 stages in flight (6 vmem ops)
  stageT(0); stageT(1); stageT(2);

#pragma unroll
  for (int s = 0; s < 4; s++) {
    int pt0 = (pairidx * 4 + s) * 128;
    floatx4 zero = {0.f, 0.f, 0.f, 0.f};
    floatx4 acc[4][2];
#pragma unroll
    for (int i = 0; i < 4; i++)
#pragma unroll
      for (int j = 0; j < 2; j++) acc[i][j] = zero;

#pragma unroll
    for (int k = 0; k < 6; k++) {
      int T = s * 6 + k;
      if (T < 22)      { WVM4; }   // stages T..T+2 outstanding (6 ops) -> completes T
      else if (T == 22){ WVM2; }
      else             { WVM0; }
      SCHED0();
      BAR();            // all waves have tile T in Bs[T%3]
      SCHED0();
#pragma unroll
      for (int ks = 0; ks < 2; ks++) {
        short8 af[4], bf[2];
#pragma unroll
        for (int i = 0; i < 4; i++) {
          int row = wrow + i * 16 + lr;
          af[i] = *(const short8*)&Aw[row * 384 + (((k * 8 + (ks << 2) + lq) ^ (lr & 7)) << 3)];
        }
#pragma unroll
        for (int j = 0; j < 2; j++) {
          int row = wp + j * 16 + lr;
          bf[j] = *(const short8*)&Bs[T % 3][row * 64 + ((((ks << 2) | lq) ^ (lr & 7)) << 3)];
        }
#pragma unroll
        for (int i = 0; i < 4; i++)
#pragma unroll
          for (int j = 0; j < 2; j++)
            acc[i][j] = __builtin_amdgcn_mfma_f32_16x16x32_bf16(af[i], bf[j], acc[i][j], 0, 0, 0);
      }
      SCHED0();
      BAR();            // everyone done reading Bs[T%3] -> safe to overwrite
      SCHED0();
      if (T + 3 < 24) stageT(T + 3);
    }

    // epilogue s: y0 stores + register stats (stores are newer than pending stages -> counts stay safe)
#pragma unroll
    for (int i = 0; i < 4; i++) {
#pragma unroll
      for (int j = 0; j < 2; j++) {
        int o = o0 + wrow + i * 16 + lq * 4;
        int p = pt0 + wp + j * 16 + lr;
        uint2 pk;
        pk.x = (u32)f2b(acc[i][j][0]) | ((u32)f2b(acc[i][j][1]) << 16);
        pk.y = (u32)f2b(acc[i][j][2]) | ((u32)f2b(acc[i][j][3]) << 16);
        *(uint2*)&y0[(size_t)p * 256 + o] = pk;
      }
#pragma unroll
      for (int r = 0; r < 4; r++) {
        float v0 = acc[i][0][r], v1 = acc[i][1][r];
        sa[i][r] += v0 + v1;
        qa[i][r] += v0 * v0 + v1 * v1;
      }
    }
  }

  // ---- stats flush: shfl-reduce over lr, LDS-combine across p-waves, one global atomic ----
#pragma unroll
  for (int i = 0; i < 4; i++)
#pragma unroll
    for (int r = 0; r < 4; r++)
#pragma unroll
      for (int m = 8; m >= 1; m >>= 1) {
        sa[i][r] += __shfl_xor(sa[i][r], m);
        qa[i][r] += __shfl_xor(qa[i][r], m);
      }
  __syncthreads();
  float* red = (float*)&Bs[0][0];
  if (t < 256) red[t] = 0.f;
  __syncthreads();
  if (lr == 0) {
#pragma unroll
    for (int i = 0; i < 4; i++)
#pragma unroll
      for (int r = 0; r < 4; r++) {
        int o = wrow + i * 16 + lq * 4 + r;     // local channel [0,128)
        atomicAdd(&red[o], sa[i][r]);
        atomicAdd(&red[128 + o], qa[i][r]);
      }
  }
  __syncthreads();
  if (t < 128) {
    atomicAdd(&sum0[o0 + t], red[t]);
    atomicAdd(&sq0[o0 + t], red[128 + t]);
  }
}

// ---------------- GEMM2: A-resident (128o x 256k), stream 2x 256p tiles, fused BN0 + stats1 ----------------
// (exact r5 code — passing; gets the pipeline treatment once gemm1 validates it)
__global__ __launch_bounds__(512, 2) void gemm2_k(const u16* __restrict__ w1b, const u16* __restrict__ y0,
                                                  const float* __restrict__ sum0, const float* __restrict__ sq0,
                                                  const float* __restrict__ gamma0, const float* __restrict__ beta0,
                                                  float* __restrict__ sum1, float* __restrict__ sq1,
                                                  u16* __restrict__ y1) {
  __shared__ u16 Aw[128 * 256];     // 64KB resident weights (o-half)
  __shared__ u16 Bs[2][256 * 64];   // 2x32KB dbuf, reg-staged with BN0 transform
  __shared__ float ssc[256], ssh[256];
  int t = threadIdx.x;
  int bid = blockIdx.x;
  int ohalf = (bid >> 3) & 1;
  int pairidx = (bid & 7) | ((bid >> 4) << 3);
  int o0 = ohalf * 128;
  int lane = t & 63, wave = t >> 6;
  int wrow = (wave >> 2) * 64;      // o within half
  int wp = (wave & 3) * 64;         // p-offset (4 groups of 64)
  int lr = lane & 15, lq = lane >> 4;
  if (t < 256) {                    // fused bnparam0
    float mean = sum0[t] * (1.f / 65536.f);
    float var = fmaxf(sq0[t] * (1.f / 65536.f) - mean * mean, 0.f);
    float r = rsqrtf(var + 1e-5f);
    float sc = gamma0[t] * r;
    ssc[t] = sc;
    ssh[t] = beta0[t] - mean * sc;
  }
  // ---- A-load: 8 glds16/thread ----
#pragma unroll
  for (int it = 0; it < 8; it++) {
    u32 off = (u32)it * 8192 + (u32)t * 16;      // byte offset (512B rows)
    int row = off >> 9;
    int c16 = (off & 511) >> 4;
    glds16(w1b + (size_t)(o0 + row) * 256 + ((c16 ^ (row & 7)) << 3),
           (char*)Aw + (size_t)it * 8192 + (size_t)wave * 1024);
  }

  // B staging ids: 4 per thread -> (row, phys chunk)
  int brow[4], bpc[4], bch[4];
#pragma unroll
  for (int i = 0; i < 4; i++) {
    int id = t + i * 512;
    brow[i] = id >> 3; bpc[i] = id & 7;
    bch[i] = (bpc[i] ^ (brow[i] & 7)) * 8;       // pre-swizzled logical source chunk
  }
  float sa[4][4], qa[4][4];
#pragma unroll
  for (int i = 0; i < 4; i++)
#pragma unroll
    for (int r = 0; r < 4; r++) { sa[i][r] = 0.f; qa[i][r] = 0.f; }

  __syncthreads();                  // ssc/ssh visible + A resident

  for (int s = 0; s < 2; s++) {
    int pt0 = (pairidx * 2 + s) * 256;
    uint4 rg[4];
    auto loadB = [&](int k0) {
#pragma unroll
      for (int i = 0; i < 4; i++)
        rg[i] = *(const uint4*)(y0 + (size_t)(pt0 + brow[i]) * 256 + k0 + bch[i]);
    };
    auto xformB = [&](int k0, int bufi) {
#pragma unroll
      for (int i = 0; i < 4; i++) {
        u32 rw[4] = {rg[i].x, rg[i].y, rg[i].z, rg[i].w};
        u32 ow[4];
#pragma unroll
        for (int w = 0; w < 4; w++) {
          int k = k0 + bch[i] + w * 2;
          float v0 = b2f((u16)(rw[w] & 0xffffu));
          float v1 = b2f((u16)(rw[w] >> 16));
          v0 = fmaxf(v0 * ssc[k] + ssh[k], 0.f);
          v1 = fmaxf(v1 * ssc[k + 1] + ssh[k + 1], 0.f);
          ow[w] = (u32)f2b(v0) | ((u32)f2b(v1) << 16);
        }
        uint4 ov; ov.x = ow[0]; ov.y = ow[1]; ov.z = ow[2]; ov.w = ow[3];
        *(uint4*)&Bs[bufi][brow[i] * 64 + bpc[i] * 8] = ov;   // contiguous 1KB/wave-op
      }
    };
    floatx4 zero = {0.f, 0.f, 0.f, 0.f};
    floatx4 acc[4][4];
#pragma unroll
    for (int i = 0; i < 4; i++)
#pragma unroll
      for (int j = 0; j < 4; j++) acc[i][j] = zero;
    auto compute = [&](int k0, int bufi) {
#pragma unroll
      for (int ks = 0; ks < 2; ks++) {
        short8 af[4], bf[4];
#pragma unroll
        for (int i = 0; i < 4; i++) {
          int row = wrow + i * 16 + lr;
          af[i] = *(const short8*)&Aw[row * 256 + ((((k0 >> 3) + (ks << 2) + lq) ^ (lr & 7)) << 3)];
        }
#pragma unroll
        for (int j = 0; j < 4; j++) {
          int row = wp + j * 16 + lr;
          bf[j] = *(const short8*)&Bs[bufi][row * 64 + ((((ks << 2) | lq) ^ (lr & 7)) << 3)];
        }
#pragma unroll
        for (int i = 0; i < 4; i++)
#pragma unroll
          for (int j = 0; j < 4; j++)
            acc[i][j] = __builtin_amdgcn_mfma_f32_16x16x32_bf16(af[i], bf[j], acc[i][j], 0, 0, 0);
      }
    };

    loadB(0);
    xformB(0, 0);
    __syncthreads();              // buf0 visible
#pragma unroll
    for (int k0i = 0; k0i < 4; k0i++) {
      if (k0i < 3) loadB((k0i + 1) * 64);        // issue early; regs used after compute
      compute(k0i * 64, k0i & 1);
      __syncthreads();
      if (k0i < 3) {
        xformB((k0i + 1) * 64, (k0i + 1) & 1);
        __syncthreads();
      }
    }
    // y1 stores + reg stats
#pragma unroll
    for (int i = 0; i < 4; i++) {
#pragma unroll
      for (int j = 0; j < 4; j++) {
        int o = o0 + wrow + i * 16 + lq * 4;
        int p = pt0 + wp + j * 16 + lr;
        uint2 pk;
        pk.x = (u32)f2b(acc[i][j][0]) | ((u32)f2b(acc[i][j][1]) << 16);
        pk.y = (u32)f2b(acc[i][j][2]) | ((u32)f2b(acc[i][j][3]) << 16);
        *(uint2*)&y1[(size_t)p * 256 + o] = pk;
      }
#pragma unroll
      for (int r = 0; r < 4; r++) {
        float v0 = acc[i][0][r], v1 = acc[i][1][r], v2 = acc[i][2][r], v3 = acc[i][3][r];
        sa[i][r] += v0 + v1 + v2 + v3;
        qa[i][r] += v0 * v0 + v1 * v1 + v2 * v2 + v3 * v3;
      }
    }
  }

#pragma unroll
  for (int i = 0; i < 4; i++)
#pragma unroll
    for (int r = 0; r < 4; r++)
#pragma unroll
      for (int m = 8; m >= 1; m >>= 1) {
        sa[i][r] += __shfl_xor(sa[i][r], m);
        qa[i][r] += __shfl_xor(qa[i][r], m);
      }
  __syncthreads();
  float* red = (float*)&Bs[0][0];
  if (t < 256) red[t] = 0.f;
  __syncthreads();
  if (lr == 0) {
#pragma unroll
    for (int i = 0; i < 4; i++)
#pragma unroll
      for (int r = 0; r < 4; r++) {
        int o = wrow + i * 16 + lq * 4 + r;
        atomicAdd(&red[o], sa[i][r]);
        atomicAdd(&red[128 + o], qa[i][r]);
      }
  }
  __syncthreads();
  if (t < 128) {
    atomicAdd(&sum1[o0 + t], red[t]);
    atomicAdd(&sq1[o0 + t], red[128 + t]);
  }
}

// ---------------- finalize: fused BN1 params + BN1+ReLU + transpose -> [b][o][n] fp32 ----------------
__global__ void finalize_k(const u16* __restrict__ y1, const float* __restrict__ sum1,
                           const float* __restrict__ sq1, const float* __restrict__ gamma1,
                           const float* __restrict__ beta1, float* __restrict__ out) {
  __shared__ float tile[64][65];
  __shared__ float fs[64], fh[64];
  int b = blockIdx.z, o0 = blockIdx.y * 64, n0 = blockIdx.x * 64;
  int t = threadIdx.x;
  if (t < 64) {
    int o = o0 + t;
    float mean = sum1[o] * (1.f / 65536.f);
    float var = fmaxf(sq1[o] * (1.f / 65536.f) - mean * mean, 0.f);
    float r = rsqrtf(var + 1e-5f);
    float sc = gamma1[o] * r;
    fs[t] = sc;
    fh[t] = beta1[o] - mean * sc;
  }
  __syncthreads();
  int pl = t >> 2, ch = (t & 3) * 16;
  const u16* src = y1 + ((size_t)(b * 8192 + n0 + pl)) * 256 + o0 + ch;
  uint4 r0 = *(const uint4*)src;
  uint4 r1 = *(const uint4*)(src + 8);
  u16 hv[16];
  *(uint4*)&hv[0] = r0;
  *(uint4*)&hv[8] = r1;
#pragma unroll
  for (int e = 0; e < 16; e++) {
    float v = b2f(hv[e]) * fs[ch + e] + fh[ch + e];
    tile[pl][ch + e] = fmaxf(v, 0.f);
  }
  __syncthreads();
  int ol = t >> 2, nch = (t & 3) * 16;
  float* dst = out + ((size_t)(b * 256 + o0 + ol)) * 8192 + n0 + nch;
#pragma unroll
  for (int j = 0; j < 16; j += 4) {
    float4 v = make_float4(tile[nch + j][ol], tile[nch + j + 1][ol],
                           tile[nch + j + 2][ol], tile[nch + j + 3][ol]);
    *(float4*)(dst + j) = v;
  }
}

extern "C" void kernel_launch(void* const* d_in, const int* in_sizes, int n_in,
                              void* d_out, int out_size, void* d_ws, size_t ws_size,
                              hipStream_t stream) {
  const float* xyz1      = (const float*)d_in[0];
  const float* xyz2      = (const float*)d_in[1];
  const float* features1 = (const float*)d_in[2];
  const float* features2 = (const float*)d_in[3];
  const float* conv_w0   = (const float*)d_in[4];
  const float* gamma0    = (const float*)d_in[5];
  const float* beta0     = (const float*)d_in[6];
  const float* conv_w1   = (const float*)d_in[7];
  const float* gamma1    = (const float*)d_in[8];
  const float* beta1     = (const float*)d_in[9];
  float* out = (float*)d_out;

  char* ws = (char*)d_ws;
  size_t off = 0;
  auto alloc = [&](size_t bytes) {
    char* p = ws + off;
    off = (off + bytes + 4095) & ~(size_t)4095;
    return p;
  };
  float*  sums = (float*)alloc(4 * 256 * 4);            // sum0, sq0, sum1, sq1
  u16*    w0b  = (u16*)alloc(256 * 384 * 2);
  u16*    w1b  = (u16*)alloc(256 * 256 * 2);
  float2* cand = (float2*)alloc((size_t)8 * 65536 * 8); // 4MB
  u16*    f1t  = (u16*)alloc((size_t)65536 * 128 * 2);
  u16*    f2t  = (u16*)alloc((size_t)16384 * 256 * 2);
  u16*    y0   = (u16*)alloc((size_t)65536 * 256 * 2);
  u16*    y1   = (u16*)alloc((size_t)65536 * 256 * 2);

  prep_all_k<<<dim3(4224), 256, 0, stream>>>(xyz1, xyz2, cand, features1, f1t,
                                             features2, f2t, conv_w0, w0b, conv_w1, w1b, sums);
  gemm1_k<<<dim3(256), 512, 0, stream>>>(w0b, f1t, f2t, cand, sums + 0, sums + 256, y0);
  gemm2_k<<<dim3(256), 512, 0, stream>>>(w1b, y0, sums + 0, sums + 256, gamma0, beta0,
                                         sums + 512, sums + 768, y1);
  finalize_k<<<dim3(128, 4, 8), 256, 0, stream>>>(y1, sums + 512, sums + 768, gamma1, beta1, out);
}